// Round 1
// baseline (717.480 us; speedup 1.0000x reference)
//
#include <hip/hip_runtime.h>

#define NUM_ENTITIES 102400
#define EMB_DIM 256
#define BATCH 512

#define BM 128
#define BN 128
#define DT 32

// x[b][d] = ent[h_idx[b]][d] + rel[r_idx[b]][d]
__global__ __launch_bounds__(EMB_DIM) void make_x_kernel(
    const float* __restrict__ ent, const float* __restrict__ rel,
    const int* __restrict__ h_idx, const int* __restrict__ r_idx,
    float* __restrict__ x) {
  const int b = blockIdx.x;
  const int d = threadIdx.x;
  const int h = h_idx[b];
  const int r = r_idx[b];
  x[b * EMB_DIM + d] = ent[h * EMB_DIM + d] + rel[r * EMB_DIM + d];
}

// out[b][n] = -sum_d |x[b][d] - ent[n][d]|
// 128x128 output tile per 256-thread block; 8x8 acc per thread; D tiled by 32.
__global__ __launch_bounds__(256) void transe_l1_kernel(
    const float* __restrict__ ent, const float* __restrict__ x,
    float* __restrict__ out) {
  __shared__ float xT[DT][BM];  // transposed: xT[dd][b]
  __shared__ float eT[DT][BN];  // transposed: eT[dd][n]

  const int n0 = blockIdx.x * BN;
  const int b0 = blockIdx.y * BM;
  const int tid = threadIdx.x;
  const int tx = tid & 15;   // entity sub-tile  (8 entities)
  const int ty = tid >> 4;   // batch sub-tile   (8 batch rows)

  // staging: 2 threads per row, 16 floats (4x float4) each
  const int s_row = tid >> 1;
  const int s_half = tid & 1;

  float acc[8][8];
#pragma unroll
  for (int i = 0; i < 8; ++i)
#pragma unroll
    for (int j = 0; j < 8; ++j) acc[i][j] = 0.0f;

  for (int d0 = 0; d0 < EMB_DIM; d0 += DT) {
    // ---- stage x tile (transposed) ----
    {
      const float4* src =
          (const float4*)&x[(b0 + s_row) * EMB_DIM + d0 + s_half * 16];
#pragma unroll
      for (int q = 0; q < 4; ++q) {
        float4 v = src[q];
        const int dd = s_half * 16 + q * 4;
        xT[dd + 0][s_row] = v.x;
        xT[dd + 1][s_row] = v.y;
        xT[dd + 2][s_row] = v.z;
        xT[dd + 3][s_row] = v.w;
      }
    }
    // ---- stage entity tile (transposed) ----
    {
      const float4* src =
          (const float4*)&ent[(size_t)(n0 + s_row) * EMB_DIM + d0 + s_half * 16];
#pragma unroll
      for (int q = 0; q < 4; ++q) {
        float4 v = src[q];
        const int dd = s_half * 16 + q * 4;
        eT[dd + 0][s_row] = v.x;
        eT[dd + 1][s_row] = v.y;
        eT[dd + 2][s_row] = v.z;
        eT[dd + 3][s_row] = v.w;
      }
    }
    __syncthreads();

    // ---- compute: outer-product accumulate ----
#pragma unroll 4
    for (int dd = 0; dd < DT; ++dd) {
      float xv[8], ev[8];
      *(float4*)&xv[0] = *(const float4*)&xT[dd][ty * 8];
      *(float4*)&xv[4] = *(const float4*)&xT[dd][ty * 8 + 4];
      *(float4*)&ev[0] = *(const float4*)&eT[dd][tx * 8];
      *(float4*)&ev[4] = *(const float4*)&eT[dd][tx * 8 + 4];
#pragma unroll
      for (int i = 0; i < 8; ++i)
#pragma unroll
        for (int j = 0; j < 8; ++j) acc[i][j] += fabsf(xv[i] - ev[j]);
    }
    __syncthreads();
  }

  // ---- epilogue: negate + coalesced float4 stores ----
#pragma unroll
  for (int i = 0; i < 8; ++i) {
    const int b = b0 + ty * 8 + i;
    float* dst = &out[(size_t)b * NUM_ENTITIES + n0 + tx * 8];
    float4 o0 = make_float4(-acc[i][0], -acc[i][1], -acc[i][2], -acc[i][3]);
    float4 o1 = make_float4(-acc[i][4], -acc[i][5], -acc[i][6], -acc[i][7]);
    ((float4*)dst)[0] = o0;
    ((float4*)dst)[1] = o1;
  }
}

extern "C" void kernel_launch(void* const* d_in, const int* in_sizes, int n_in,
                              void* d_out, int out_size, void* d_ws,
                              size_t ws_size, hipStream_t stream) {
  const float* ent = (const float*)d_in[0];
  const float* rel = (const float*)d_in[1];
  const int* h_idx = (const int*)d_in[2];
  const int* r_idx = (const int*)d_in[3];
  float* out = (float*)d_out;
  float* x = (float*)d_ws;  // BATCH * EMB_DIM * 4 = 512 KiB scratch

  make_x_kernel<<<BATCH, EMB_DIM, 0, stream>>>(ent, rel, h_idx, r_idx, x);

  dim3 grid(NUM_ENTITIES / BN, BATCH / BM);
  transe_l1_kernel<<<grid, 256, 0, stream>>>(ent, x, out);
}

// Round 3
// 584.747 us; speedup vs baseline: 1.2270x; 1.2270x over previous
//
#include <hip/hip_runtime.h>
#include <stdint.h>

#define NE 102400
#define DIM 256
#define NBATCH 512

#define BM 128
#define BN 128
#define DT 64          // f32 elements of D per tile
#define DP (DT / 2)    // packed f16 pair-rows per tile

typedef _Float16 h2 __attribute__((ext_vector_type(2)));

static __device__ __forceinline__ uint32_t pack_rtz(float a, float b) {
  auto p = __builtin_amdgcn_cvt_pkrtz(a, b);  // __fp16x2 on this toolchain
  return __builtin_bit_cast(uint32_t, p);
}

// x[b][d] = ent[h_idx[b]][d] + rel[r_idx[b]][d]
__global__ __launch_bounds__(DIM) void make_x_kernel(
    const float* __restrict__ ent, const float* __restrict__ rel,
    const int* __restrict__ h_idx, const int* __restrict__ r_idx,
    float* __restrict__ x) {
  const int b = blockIdx.x;
  const int d = threadIdx.x;
  const int h = h_idx[b];
  const int r = r_idx[b];
  x[b * DIM + d] = ent[h * DIM + d] + rel[r * DIM + d];
}

// out[b][n] = -sum_d |x[b][d] - ent[n][d]|
// 128x128 tile / 256 threads; 8x8 acc per thread (two stride-64 groups of 4);
// packed-f16 diffs, f32 accumulation via v_dot2_f32_f16 with (-1,-1).
__global__ __launch_bounds__(256) void transe_l1_f16_kernel(
    const float* __restrict__ ent, const float* __restrict__ x,
    float* __restrict__ out) {
  __shared__ uint32_t xT[DP][BM];  // xT[k][b]: f16 pair for d=(2k,2k+1)
  __shared__ uint32_t eT[DP][BN];  // eT[k][n]

  const int n0 = blockIdx.x * BN;
  const int b0 = blockIdx.y * BM;
  const int tid = threadIdx.x;
  const int tx = tid & 15;   // entity group base
  const int ty = tid >> 4;   // batch group base

  // staging: 2 threads per row, 32 floats (8x float4) each
  const int s_row = tid >> 1;
  const int s_half = tid & 1;

  float acc[8][8];
#pragma unroll
  for (int i = 0; i < 8; ++i)
#pragma unroll
    for (int j = 0; j < 8; ++j) acc[i][j] = 0.0f;

  const uint32_t neg_one2 = 0xBC00BC00u;  // (f16)-1.0 x2

  for (int d0 = 0; d0 < DIM; d0 += DT) {
    // ---- stage x tile (transposed, packed f16) ----
    {
      const float4* src =
          (const float4*)&x[(b0 + s_row) * DIM + d0 + s_half * 32];
#pragma unroll
      for (int q = 0; q < 8; ++q) {
        float4 v = src[q];
        const int k = s_half * 16 + q * 2;
        xT[k + 0][s_row] = pack_rtz(v.x, v.y);
        xT[k + 1][s_row] = pack_rtz(v.z, v.w);
      }
    }
    // ---- stage entity tile (transposed, packed f16) ----
    {
      const float4* src =
          (const float4*)&ent[(size_t)(n0 + s_row) * DIM + d0 + s_half * 32];
#pragma unroll
      for (int q = 0; q < 8; ++q) {
        float4 v = src[q];
        const int k = s_half * 16 + q * 2;
        eT[k + 0][s_row] = pack_rtz(v.x, v.y);
        eT[k + 1][s_row] = pack_rtz(v.z, v.w);
      }
    }
    __syncthreads();

    // ---- compute ----
#pragma unroll 4
    for (int k = 0; k < DP; ++k) {
      uint32_t xw[8], ew[8];
      *(uint4*)&xw[0] = *(const uint4*)&xT[k][ty * 4];
      *(uint4*)&xw[4] = *(const uint4*)&xT[k][64 + ty * 4];
      *(uint4*)&ew[0] = *(const uint4*)&eT[k][tx * 4];
      *(uint4*)&ew[4] = *(const uint4*)&eT[k][64 + tx * 4];
#pragma unroll
      for (int i = 0; i < 8; ++i) {
        const h2 xv = __builtin_bit_cast(h2, xw[i]);
#pragma unroll
        for (int j = 0; j < 8; ++j) {
          const h2 dv = xv - __builtin_bit_cast(h2, ew[j]);
          const uint32_t a = __builtin_bit_cast(uint32_t, dv) & 0x7fff7fffu;
          // acc += dot2(|d|, (-1,-1))  ==> acc -= |d|.x + |d|.y
          asm("v_dot2_f32_f16 %0, %1, %2, %0"
              : "+v"(acc[i][j])
              : "v"(a), "v"(neg_one2));
        }
      }
    }
    __syncthreads();
  }

  // ---- epilogue: acc already negated; float4 stores ----
#pragma unroll
  for (int i = 0; i < 8; ++i) {
    const int b = b0 + (i >> 2) * 64 + ty * 4 + (i & 3);
    float* dst = &out[(size_t)b * NE + n0];
    *(float4*)&dst[tx * 4] = *(const float4*)&acc[i][0];
    *(float4*)&dst[64 + tx * 4] = *(const float4*)&acc[i][4];
  }
}

extern "C" void kernel_launch(void* const* d_in, const int* in_sizes, int n_in,
                              void* d_out, int out_size, void* d_ws,
                              size_t ws_size, hipStream_t stream) {
  const float* ent = (const float*)d_in[0];
  const float* rel = (const float*)d_in[1];
  const int* h_idx = (const int*)d_in[2];
  const int* r_idx = (const int*)d_in[3];
  float* out = (float*)d_out;
  float* x = (float*)d_ws;  // NBATCH * DIM * 4 = 512 KiB scratch

  make_x_kernel<<<NBATCH, DIM, 0, stream>>>(ent, rel, h_idx, r_idx, x);

  dim3 grid(NE / BN, NBATCH / BM);
  transe_l1_f16_kernel<<<grid, 256, 0, stream>>>(ent, x, out);
}

// Round 4
// 232.984 us; speedup vs baseline: 3.0795x; 2.5098x over previous
//
#include <hip/hip_runtime.h>
#include <stdint.h>

#define NE 102400
#define DIM 256
#define NB 512

#define BM 128        // batch tile
#define BN 128        // entity tile
#define DT 128        // f32 dims per stage
#define KT (DT / 4)   // packed u32 rows per stage = 32

#define SQ 384.0f
#define NINV (-1.0f / 384.0f)

// Quantize x[b] = ent[h[b]] + rel[r[b]] to u8 (zero-point 128, scale 384),
// packed 4/dword: xq[b][k] covers dims 4k..4k+3.
__global__ __launch_bounds__(64) void make_xq_kernel(
    const float* __restrict__ ent, const float* __restrict__ rel,
    const int* __restrict__ h_idx, const int* __restrict__ r_idx,
    uint32_t* __restrict__ xq) {
  const int b = blockIdx.x;
  const int t = threadIdx.x;  // 64 threads, 4 dims each
  const float4 e = *(const float4*)&ent[(size_t)h_idx[b] * DIM + t * 4];
  const float4 r = *(const float4*)&rel[(size_t)r_idx[b] * DIM + t * 4];
  uint32_t q = 0;
  asm("v_cvt_pk_u8_f32 %0, %1, 0, %0" : "+v"(q) : "v"(fmaf(e.x + r.x, SQ, 128.5f)));
  asm("v_cvt_pk_u8_f32 %0, %1, 1, %0" : "+v"(q) : "v"(fmaf(e.y + r.y, SQ, 128.5f)));
  asm("v_cvt_pk_u8_f32 %0, %1, 2, %0" : "+v"(q) : "v"(fmaf(e.z + r.z, SQ, 128.5f)));
  asm("v_cvt_pk_u8_f32 %0, %1, 3, %0" : "+v"(q) : "v"(fmaf(e.w + r.w, SQ, 128.5f)));
  xq[(size_t)b * (DIM / 4) + t] = q;
}

// out[b][n] = -sum_d |x[b][d] - ent[n][d]|  via u8 SAD.
// 128x128 tile / 256 threads; 8x8 acc (two stride-64 groups of 4);
// inner op: v_sad_u8 (4 dims per instruction, accumulates in u32).
__global__ __launch_bounds__(256, 4) void transe_sad_kernel(
    const float* __restrict__ ent, const uint32_t* __restrict__ xq,
    float* __restrict__ out) {
  __shared__ uint32_t xT[KT][BM];  // xT[k][b]
  __shared__ uint32_t eT[KT][BN];  // eT[k][n]

  const int n0 = blockIdx.x * BN;
  const int b0 = blockIdx.y * BM;
  const int tid = threadIdx.x;
  const int tx = tid & 15;
  const int ty = tid >> 4;
  const int s_row = tid >> 1;   // 2 threads per row
  const int s_half = tid & 1;   // each covers 64 dims (16 u32)

  uint32_t acc[8][8];
#pragma unroll
  for (int i = 0; i < 8; ++i)
#pragma unroll
    for (int j = 0; j < 8; ++j) acc[i][j] = 0u;

  for (int d0 = 0; d0 < DIM; d0 += DT) {
    // ---- stage x tile (already quantized): 4x uint4 per thread ----
    {
      const uint4* src =
          (const uint4*)&xq[(size_t)(b0 + s_row) * (DIM / 4) + d0 / 4 + s_half * 16];
#pragma unroll
      for (int q = 0; q < 4; ++q) {
        uint4 v = src[q];
        const int k = s_half * 16 + q * 4;
        xT[k + 0][s_row] = v.x;
        xT[k + 1][s_row] = v.y;
        xT[k + 2][s_row] = v.z;
        xT[k + 3][s_row] = v.w;
      }
    }
    // ---- stage entity tile: load f32, quantize to packed u8 ----
    {
      const float4* src =
          (const float4*)&ent[(size_t)(n0 + s_row) * DIM + d0 + s_half * 64];
#pragma unroll
      for (int q = 0; q < 16; ++q) {
        float4 v = src[q];
        uint32_t w = 0;
        asm("v_cvt_pk_u8_f32 %0, %1, 0, %0" : "+v"(w) : "v"(fmaf(v.x, SQ, 128.5f)));
        asm("v_cvt_pk_u8_f32 %0, %1, 1, %0" : "+v"(w) : "v"(fmaf(v.y, SQ, 128.5f)));
        asm("v_cvt_pk_u8_f32 %0, %1, 2, %0" : "+v"(w) : "v"(fmaf(v.z, SQ, 128.5f)));
        asm("v_cvt_pk_u8_f32 %0, %1, 3, %0" : "+v"(w) : "v"(fmaf(v.w, SQ, 128.5f)));
        eT[s_half * 16 + q][s_row] = w;
      }
    }
    __syncthreads();

    // ---- compute: 64 SADs per k (4 dims each) ----
#pragma unroll 2
    for (int k = 0; k < KT; ++k) {
      uint32_t xw[8], ew[8];
      *(uint4*)&xw[0] = *(const uint4*)&xT[k][ty * 4];
      *(uint4*)&xw[4] = *(const uint4*)&xT[k][64 + ty * 4];
      *(uint4*)&ew[0] = *(const uint4*)&eT[k][tx * 4];
      *(uint4*)&ew[4] = *(const uint4*)&eT[k][64 + tx * 4];
#pragma unroll
      for (int i = 0; i < 8; ++i)
#pragma unroll
        for (int j = 0; j < 8; ++j)
          asm("v_sad_u8 %0, %1, %2, %0"
              : "+v"(acc[i][j])
              : "v"(xw[i]), "v"(ew[j]));
    }
    __syncthreads();
  }

  // ---- epilogue: out = -acc/384, float4 stores ----
#pragma unroll
  for (int i = 0; i < 8; ++i) {
    const int b = b0 + ((i & 4) << 4) + ty * 4 + (i & 3);
    float* dst = &out[(size_t)b * NE + n0];
    float4 o0, o1;
    o0.x = (float)acc[i][0] * NINV;
    o0.y = (float)acc[i][1] * NINV;
    o0.z = (float)acc[i][2] * NINV;
    o0.w = (float)acc[i][3] * NINV;
    o1.x = (float)acc[i][4] * NINV;
    o1.y = (float)acc[i][5] * NINV;
    o1.z = (float)acc[i][6] * NINV;
    o1.w = (float)acc[i][7] * NINV;
    *(float4*)&dst[tx * 4] = o0;
    *(float4*)&dst[64 + tx * 4] = o1;
  }
}

extern "C" void kernel_launch(void* const* d_in, const int* in_sizes, int n_in,
                              void* d_out, int out_size, void* d_ws,
                              size_t ws_size, hipStream_t stream) {
  const float* ent = (const float*)d_in[0];
  const float* rel = (const float*)d_in[1];
  const int* h_idx = (const int*)d_in[2];
  const int* r_idx = (const int*)d_in[3];
  float* out = (float*)d_out;
  uint32_t* xq = (uint32_t*)d_ws;  // NB * DIM/4 * 4 B = 128 KiB scratch

  make_xq_kernel<<<NB, 64, 0, stream>>>(ent, rel, h_idx, r_idx, xq);

  dim3 grid(NE / BN, NB / BM);
  transe_sad_kernel<<<grid, 256, 0, stream>>>(ent, xq, out);
}

// Round 6
// 134.488 us; speedup vs baseline: 5.3349x; 1.7324x over previous
//
#include <hip/hip_runtime.h>
#include <stdint.h>

#define NE 102400
#define DIM 256
#define NB 512
#define KROW (DIM / 4)   // 64 packed u32 per row

#define BM 128        // batch tile
#define BN 128        // entity tile
#define DT 128        // f32 dims per stage
#define KT (DT / 4)   // packed u32 rows per stage = 32

#define SQ 384.0f
#define NINV (-1.0f / 384.0f)

#define XQ_BYTES ((size_t)NB * KROW * 4)        // 128 KiB
#define EQ_BYTES ((size_t)NE * KROW * 4)        // 25 MiB

typedef float vf4 __attribute__((ext_vector_type(4)));

static __device__ __forceinline__ uint32_t quant4(float a, float b, float c,
                                                  float d) {
  uint32_t q = 0;
  asm("v_cvt_pk_u8_f32 %0, %1, 0, %0" : "+v"(q) : "v"(fmaf(a, SQ, 128.5f)));
  asm("v_cvt_pk_u8_f32 %0, %1, 1, %0" : "+v"(q) : "v"(fmaf(b, SQ, 128.5f)));
  asm("v_cvt_pk_u8_f32 %0, %1, 2, %0" : "+v"(q) : "v"(fmaf(c, SQ, 128.5f)));
  asm("v_cvt_pk_u8_f32 %0, %1, 3, %0" : "+v"(q) : "v"(fmaf(d, SQ, 128.5f)));
  return q;
}

// xq[b][k] = quantized (ent[h[b]] + rel[r[b]]), u8 zero-point 128, scale 384.
__global__ __launch_bounds__(64) void make_xq_kernel(
    const float* __restrict__ ent, const float* __restrict__ rel,
    const int* __restrict__ h_idx, const int* __restrict__ r_idx,
    uint32_t* __restrict__ xq) {
  const int b = blockIdx.x;
  const int t = threadIdx.x;
  const float4 e = *(const float4*)&ent[(size_t)h_idx[b] * DIM + t * 4];
  const float4 r = *(const float4*)&rel[(size_t)r_idx[b] * DIM + t * 4];
  xq[(size_t)b * KROW + t] = quant4(e.x + r.x, e.y + r.y, e.z + r.z, e.w + r.w);
}

// eq[n][k] = quantized ent[n], 4 rows per 256-thread block.
__global__ __launch_bounds__(256) void quant_ent_kernel(
    const float* __restrict__ ent, uint32_t* __restrict__ eq) {
  const int n = blockIdx.x * 4 + (threadIdx.x >> 6);
  const int t = threadIdx.x & 63;
  const float4 v = *(const float4*)&ent[(size_t)n * DIM + t * 4];
  eq[(size_t)n * KROW + t] = quant4(v.x, v.y, v.z, v.w);
}

// out[b][n] = -sum_d |x[b][d] - ent[n][d]| via u8 SAD, both operands
// pre-quantized. 128x128 tile / 256 threads; 8x8 acc per thread.
__global__ __launch_bounds__(256, 4) void transe_sad_q_kernel(
    const uint32_t* __restrict__ eq, const uint32_t* __restrict__ xq,
    float* __restrict__ out) {
  __shared__ uint32_t xT[KT][BM];  // xT[k][b]
  __shared__ uint32_t eT[KT][BN];  // eT[k][n]

  const int n0 = blockIdx.x * BN;
  const int b0 = blockIdx.y * BM;
  const int tid = threadIdx.x;
  const int tx = tid & 15;
  const int ty = tid >> 4;
  const int s_row = tid >> 1;   // 2 threads per row
  const int s_half = tid & 1;   // 16 u32 (64 dims) each

  uint32_t acc[8][8];
#pragma unroll
  for (int i = 0; i < 8; ++i)
#pragma unroll
    for (int j = 0; j < 8; ++j) acc[i][j] = 0u;

  for (int d0 = 0; d0 < DIM; d0 += DT) {
    // ---- stage x tile ----
    {
      const uint4* src =
          (const uint4*)&xq[(size_t)(b0 + s_row) * KROW + d0 / 4 + s_half * 16];
#pragma unroll
      for (int q = 0; q < 4; ++q) {
        uint4 v = src[q];
        const int k = s_half * 16 + q * 4;
        xT[k + 0][s_row] = v.x;
        xT[k + 1][s_row] = v.y;
        xT[k + 2][s_row] = v.z;
        xT[k + 3][s_row] = v.w;
      }
    }
    // ---- stage entity tile (pre-quantized) ----
    {
      const uint4* src =
          (const uint4*)&eq[(size_t)(n0 + s_row) * KROW + d0 / 4 + s_half * 16];
#pragma unroll
      for (int q = 0; q < 4; ++q) {
        uint4 v = src[q];
        const int k = s_half * 16 + q * 4;
        eT[k + 0][s_row] = v.x;
        eT[k + 1][s_row] = v.y;
        eT[k + 2][s_row] = v.z;
        eT[k + 3][s_row] = v.w;
      }
    }
    __syncthreads();

#pragma unroll 2
    for (int k = 0; k < KT; ++k) {
      uint32_t xw[8], ew[8];
      *(uint4*)&xw[0] = *(const uint4*)&xT[k][ty * 4];
      *(uint4*)&xw[4] = *(const uint4*)&xT[k][64 + ty * 4];
      *(uint4*)&ew[0] = *(const uint4*)&eT[k][tx * 4];
      *(uint4*)&ew[4] = *(const uint4*)&eT[k][64 + tx * 4];
#pragma unroll
      for (int i = 0; i < 8; ++i)
#pragma unroll
        for (int j = 0; j < 8; ++j)
          asm("v_sad_u8 %0, %1, %2, %0"
              : "+v"(acc[i][j])
              : "v"(xw[i]), "v"(ew[j]));
    }
    __syncthreads();
  }

  // ---- epilogue: out = -acc/384, non-temporal stores ----
#pragma unroll
  for (int i = 0; i < 8; ++i) {
    const int b = b0 + ((i & 4) << 4) + ty * 4 + (i & 3);
    float* dst = &out[(size_t)b * NE + n0];
    vf4 o0, o1;
    o0.x = (float)acc[i][0] * NINV;
    o0.y = (float)acc[i][1] * NINV;
    o0.z = (float)acc[i][2] * NINV;
    o0.w = (float)acc[i][3] * NINV;
    o1.x = (float)acc[i][4] * NINV;
    o1.y = (float)acc[i][5] * NINV;
    o1.z = (float)acc[i][6] * NINV;
    o1.w = (float)acc[i][7] * NINV;
    __builtin_nontemporal_store(o0, (vf4*)&dst[tx * 4]);
    __builtin_nontemporal_store(o1, (vf4*)&dst[64 + tx * 4]);
  }
}

// ---- fallback (ws too small for eq): in-kernel entity quantize ----
__global__ __launch_bounds__(256, 4) void transe_sad_f32_kernel(
    const float* __restrict__ ent, const uint32_t* __restrict__ xq,
    float* __restrict__ out) {
  __shared__ uint32_t xT[KT][BM];
  __shared__ uint32_t eT[KT][BN];

  const int n0 = blockIdx.x * BN;
  const int b0 = blockIdx.y * BM;
  const int tid = threadIdx.x;
  const int tx = tid & 15;
  const int ty = tid >> 4;
  const int s_row = tid >> 1;
  const int s_half = tid & 1;

  uint32_t acc[8][8];
#pragma unroll
  for (int i = 0; i < 8; ++i)
#pragma unroll
    for (int j = 0; j < 8; ++j) acc[i][j] = 0u;

  for (int d0 = 0; d0 < DIM; d0 += DT) {
    {
      const uint4* src =
          (const uint4*)&xq[(size_t)(b0 + s_row) * KROW + d0 / 4 + s_half * 16];
#pragma unroll
      for (int q = 0; q < 4; ++q) {
        uint4 v = src[q];
        const int k = s_half * 16 + q * 4;
        xT[k + 0][s_row] = v.x;
        xT[k + 1][s_row] = v.y;
        xT[k + 2][s_row] = v.z;
        xT[k + 3][s_row] = v.w;
      }
    }
    {
      const float4* src =
          (const float4*)&ent[(size_t)(n0 + s_row) * DIM + d0 + s_half * 64];
#pragma unroll
      for (int q = 0; q < 16; ++q) {
        float4 v = src[q];
        eT[s_half * 16 + q][s_row] = quant4(v.x, v.y, v.z, v.w);
      }
    }
    __syncthreads();

#pragma unroll 2
    for (int k = 0; k < KT; ++k) {
      uint32_t xw[8], ew[8];
      *(uint4*)&xw[0] = *(const uint4*)&xT[k][ty * 4];
      *(uint4*)&xw[4] = *(const uint4*)&xT[k][64 + ty * 4];
      *(uint4*)&ew[0] = *(const uint4*)&eT[k][tx * 4];
      *(uint4*)&ew[4] = *(const uint4*)&eT[k][64 + tx * 4];
#pragma unroll
      for (int i = 0; i < 8; ++i)
#pragma unroll
        for (int j = 0; j < 8; ++j)
          asm("v_sad_u8 %0, %1, %2, %0"
              : "+v"(acc[i][j])
              : "v"(xw[i]), "v"(ew[j]));
    }
    __syncthreads();
  }

#pragma unroll
  for (int i = 0; i < 8; ++i) {
    const int b = b0 + ((i & 4) << 4) + ty * 4 + (i & 3);
    float* dst = &out[(size_t)b * NE + n0];
    vf4 o0, o1;
    o0.x = (float)acc[i][0] * NINV;
    o0.y = (float)acc[i][1] * NINV;
    o0.z = (float)acc[i][2] * NINV;
    o0.w = (float)acc[i][3] * NINV;
    o1.x = (float)acc[i][4] * NINV;
    o1.y = (float)acc[i][5] * NINV;
    o1.z = (float)acc[i][6] * NINV;
    o1.w = (float)acc[i][7] * NINV;
    __builtin_nontemporal_store(o0, (vf4*)&dst[tx * 4]);
    __builtin_nontemporal_store(o1, (vf4*)&dst[64 + tx * 4]);
  }
}

extern "C" void kernel_launch(void* const* d_in, const int* in_sizes, int n_in,
                              void* d_out, int out_size, void* d_ws,
                              size_t ws_size, hipStream_t stream) {
  const float* ent = (const float*)d_in[0];
  const float* rel = (const float*)d_in[1];
  const int* h_idx = (const int*)d_in[2];
  const int* r_idx = (const int*)d_in[3];
  float* out = (float*)d_out;

  uint32_t* xq = (uint32_t*)d_ws;
  uint32_t* eq = (uint32_t*)((char*)d_ws + XQ_BYTES);

  make_xq_kernel<<<NB, 64, 0, stream>>>(ent, rel, h_idx, r_idx, xq);

  dim3 grid(NE / BN, NB / BM);
  if (ws_size >= XQ_BYTES + EQ_BYTES) {
    quant_ent_kernel<<<NE / 4, 256, 0, stream>>>(ent, eq);
    transe_sad_q_kernel<<<grid, 256, 0, stream>>>(eq, xq, out);
  } else {
    transe_sad_f32_kernel<<<grid, 256, 0, stream>>>(ent, xq, out);
  }
}